// Round 1
// baseline (355.233 us; speedup 1.0000x reference)
//
#include <hip/hip_runtime.h>
#include <stdint.h>

typedef __bf16 bf16x8 __attribute__((ext_vector_type(8)));
typedef float  f32x4  __attribute__((ext_vector_type(4)));

#define AS1 __attribute__((address_space(1)))
#define AS3 __attribute__((address_space(3)))

static constexpr int S_DIM = 1024;   // sequence length (= N = K)
static constexpr int BM = 128;
static constexpr int BN = 128;
static constexpr int BK = 32;

// RNE fp32 -> bf16 (inputs are finite random normals; no NaN handling needed)
__device__ __forceinline__ ushort f32_to_bf16_rne(float f) {
    uint32_t u = __builtin_bit_cast(uint32_t, f);
    u += 0x7fffu + ((u >> 16) & 1u);
    return (ushort)(u >> 16);
}

// Build Wc[kq][j][8] bf16 chunks: Wc chunk (kq, j) holds W[kq*8+e][j] for e=0..7,
// where W[k][j] = (j >= k) ? w[j-k] : 0.  Chunked so the GEMM B-staging is a
// perfectly coalesced 16B-per-lane global_load_lds.
__global__ void build_wc(const float* __restrict__ w, ushort* __restrict__ Wc) {
    int c  = blockIdx.x * 256 + threadIdx.x;   // 0..131071 == kq*1024 + j
    int kq = c >> 10;
    int j  = c & 1023;
    uint32_t p[4];
#pragma unroll
    for (int h = 0; h < 4; ++h) {
        int e0 = h * 2;
        int d0 = j - (kq * 8 + e0);
        int d1 = d0 - 1;
        float v0 = (d0 >= 0) ? w[d0] : 0.0f;
        float v1 = (d1 >= 0) ? w[d1] : 0.0f;
        p[h] = (uint32_t)f32_to_bf16_rne(v0) | ((uint32_t)f32_to_bf16_rne(v1) << 16);
    }
    uint4 val = make_uint4(p[0], p[1], p[2], p[3]);
    reinterpret_cast<uint4*>(Wc)[c] = val;
}

// 128x128 output tile per block, 256 threads = 4 waves in 2x2, each wave a
// 64x64 sub-tile = 4x4 grid of 16x16x32 bf16 MFMAs.  K-loop bounded at
// j0+BN (upper-triangular Toeplitz => columns [j0, j0+BN) only need k < j0+BN).
__global__ __launch_bounds__(256) void toep_gemm(
    const float* __restrict__ x, const ushort* __restrict__ Wc,
    const float* __restrict__ bias, float* __restrict__ out)
{
    __shared__ __align__(16) ushort As[4 * BM * 8];   // [q][m][8]  (q = k/8 within K-step)
    __shared__ __align__(16) ushort Bs[4 * BN * 8];   // [q][n][8]

    const int bx = blockIdx.x;
    const int jb = 7 - (bx & 7);        // heavy column blocks first
    const int rb = bx >> 3;
    const int m0 = rb * BM;
    const int j0 = jb * BN;
    const int Kblk = j0 + BN;           // exclusive K bound (multiple of 32)

    const int tid  = threadIdx.x;
    const int lane = tid & 63;
    const int wave = tid >> 6;
    const int wm   = (wave >> 1) * 64;
    const int wn   = (wave & 1) * 64;
    const int l15  = lane & 15;
    const int quad = lane >> 4;

    f32x4 acc[4][4] = {};

    // A staging geometry: inst i covers rows i*32 + (tid>>3), k-chunk kc = tid&7 (4 fp32)
    const int a_sub_row = tid >> 3;
    const int a_kc      = tid & 7;
    const int a_q       = a_kc >> 1;
    const int a_sub     = a_kc & 1;
    // B staging geometry: global_load_lds, lane-linear 16B chunks
    const int b_n  = tid & 127;
    const int b_q  = tid >> 7;          // 0 or 1 (call 0), +2 (call 1)

    for (int k0 = 0; k0 < Kblk; k0 += BK) {
        // ---- stage A: 4 x 16B fp32 loads ----
        f32x4 av[4];
#pragma unroll
        for (int i = 0; i < 4; ++i) {
            const float* gp = x + (size_t)(m0 + i * 32 + a_sub_row) * S_DIM + k0 + a_kc * 4;
            av[i] = *reinterpret_cast<const f32x4*>(gp);
        }
        // ---- stage B: async global -> LDS, 2 x 16B per lane ----
        {
            const int kq0 = k0 >> 3;
            const ushort* g0 = Wc + ((size_t)(kq0 + b_q)     * 1024 + j0 + b_n) * 8;
            const ushort* g1 = Wc + ((size_t)(kq0 + 2 + b_q) * 1024 + j0 + b_n) * 8;
            ushort* l0 = Bs + (size_t)(wave * 64) * 8;
            ushort* l1 = Bs + (size_t)(256 + wave * 64) * 8;
            __builtin_amdgcn_global_load_lds((const AS1 void*)g0, (AS3 void*)l0, 16, 0, 0);
            __builtin_amdgcn_global_load_lds((const AS1 void*)g1, (AS3 void*)l1, 16, 0, 0);
        }
        // ---- convert A to bf16, write LDS ----
#pragma unroll
        for (int i = 0; i < 4; ++i) {
            uint32_t p0 = (uint32_t)f32_to_bf16_rne(av[i][0]) | ((uint32_t)f32_to_bf16_rne(av[i][1]) << 16);
            uint32_t p1 = (uint32_t)f32_to_bf16_rne(av[i][2]) | ((uint32_t)f32_to_bf16_rne(av[i][3]) << 16);
            int row = i * 32 + a_sub_row;
            uint32_t* lp = reinterpret_cast<uint32_t*>(&As[(size_t)(a_q * BM + row) * 8 + a_sub * 4]);
            lp[0] = p0;
            lp[1] = p1;
        }
        __syncthreads();

        // ---- fragment loads (conflict-free ds_read_b128) + 16 MFMA ----
        bf16x8 af[4], bf[4];
#pragma unroll
        for (int im = 0; im < 4; ++im) {
            int m_local = wm + im * 16 + l15;
            af[im] = *reinterpret_cast<const bf16x8*>(&As[(size_t)(quad * BM + m_local) * 8]);
        }
#pragma unroll
        for (int in = 0; in < 4; ++in) {
            int n_local = wn + in * 16 + l15;
            bf[in] = *reinterpret_cast<const bf16x8*>(&Bs[(size_t)(quad * BN + n_local) * 8]);
        }
#pragma unroll
        for (int im = 0; im < 4; ++im)
#pragma unroll
            for (int in = 0; in < 4; ++in)
                acc[im][in] = __builtin_amdgcn_mfma_f32_16x16x32_bf16(af[im], bf[in], acc[im][in], 0, 0, 0);
        __syncthreads();
    }

    // ---- epilogue: add bias, store (C/D: col = lane&15, row = quad*4 + r) ----
#pragma unroll
    for (int in = 0; in < 4; ++in) {
        int col = j0 + wn + in * 16 + l15;
        float bv = bias[col];
#pragma unroll
        for (int im = 0; im < 4; ++im) {
            int mrow = m0 + wm + im * 16 + quad * 4;
            float* op = out + (size_t)mrow * S_DIM + col;
#pragma unroll
            for (int r = 0; r < 4; ++r) {
                op[(size_t)r * S_DIM] = acc[im][in][r] + bv;
            }
        }
    }
}

extern "C" void kernel_launch(void* const* d_in, const int* in_sizes, int n_in,
                              void* d_out, int out_size, void* d_ws, size_t ws_size,
                              hipStream_t stream) {
    const float* x      = (const float*)d_in[0];   // (32, 1024, 1024) fp32
    const float* weight = (const float*)d_in[1];   // (1, 1024) fp32
    const float* bias   = (const float*)d_in[2];   // (1024,) fp32
    float* out          = (float*)d_out;           // (32, 1024, 1024) fp32

    ushort* Wc = (ushort*)d_ws;                    // 128*1024*8 ushorts = 2 MB

    // 1) materialize bf16 Toeplitz W in chunked layout
    build_wc<<<512, 256, 0, stream>>>(weight, Wc);
    // 2) triangular-aware bf16 MFMA GEMM: 256 row blocks x 8 col blocks
    toep_gemm<<<2048, 256, 0, stream>>>(x, Wc, bias, out);
}

// Round 2
// 328.808 us; speedup vs baseline: 1.0804x; 1.0804x over previous
//
#include <hip/hip_runtime.h>
#include <stdint.h>

typedef __bf16 bf16x8 __attribute__((ext_vector_type(8)));
typedef float  f32x4  __attribute__((ext_vector_type(4)));

#define AS1 __attribute__((address_space(1)))
#define AS3 __attribute__((address_space(3)))

static constexpr int S_DIM = 1024;   // sequence length (= N = K)
static constexpr int M_DIM = 32768;  // B*E rows
static constexpr int BM = 128;
static constexpr int BN = 128;
static constexpr int BK = 32;

// RNE fp32 -> bf16
__device__ __forceinline__ ushort f32_to_bf16_rne(float f) {
    uint32_t u = __builtin_bit_cast(uint32_t, f);
    u += 0x7fffu + ((u >> 16) & 1u);
    return (ushort)(u >> 16);
}
__device__ __forceinline__ uint32_t pk_bf16(float a, float b) {
    return (uint32_t)f32_to_bf16_rne(a) | ((uint32_t)f32_to_bf16_rne(b) << 16);
}

// Wc[kq][j][8] bf16 chunks: chunk (kq, j) holds W[kq*8+e][j], e=0..7,
// W[k][j] = (j >= k) ? w[j-k] : 0.
__global__ void build_wc(const float* __restrict__ w, ushort* __restrict__ Wc) {
    int c  = blockIdx.x * 256 + threadIdx.x;   // kq*1024 + j
    int kq = c >> 10;
    int j  = c & 1023;
    uint32_t p[4];
#pragma unroll
    for (int h = 0; h < 4; ++h) {
        int d0 = j - (kq * 8 + h * 2);
        int d1 = d0 - 1;
        float v0 = (d0 >= 0) ? w[d0] : 0.0f;
        float v1 = (d1 >= 0) ? w[d1] : 0.0f;
        p[h] = (uint32_t)f32_to_bf16_rne(v0) | ((uint32_t)f32_to_bf16_rne(v1) << 16);
    }
    reinterpret_cast<uint4*>(Wc)[c] = make_uint4(p[0], p[1], p[2], p[3]);
}

// Xc[kq][m][8] bf16 chunks: chunk (kq, m) holds x[m][kq*8+e], e=0..7.
// Each thread reads 64B (sector-aligned) from one row and emits two chunks.
// Writes are two lane-linear 16B streams (perfectly coalesced).
__global__ __launch_bounds__(256) void convert_x(const float* __restrict__ x,
                                                 ushort* __restrict__ Xc) {
    int id = blockIdx.x * 256 + threadIdx.x;   // 0 .. 64*32768-1
    int m  = id & (M_DIM - 1);
    int kp = id >> 15;                          // 0..63 -> kq = 2*kp, 2*kp+1
    const f32x4* p = reinterpret_cast<const f32x4*>(x + (size_t)m * S_DIM + kp * 16);
    f32x4 v0 = p[0], v1 = p[1], v2 = p[2], v3 = p[3];
    uint4 c0 = make_uint4(pk_bf16(v0[0], v0[1]), pk_bf16(v0[2], v0[3]),
                          pk_bf16(v1[0], v1[1]), pk_bf16(v1[2], v1[3]));
    uint4 c1 = make_uint4(pk_bf16(v2[0], v2[1]), pk_bf16(v2[2], v2[3]),
                          pk_bf16(v3[0], v3[1]), pk_bf16(v3[2], v3[3]));
    uint4* out = reinterpret_cast<uint4*>(Xc);
    out[(size_t)(2 * kp)     * M_DIM + m] = c0;
    out[(size_t)(2 * kp + 1) * M_DIM + m] = c1;
}

// m97-structure GEMM: 128x128 tile, BK=32, 4 waves (2x2), all staging via
// global_load_lds width=16.  K-loop bounded at j0+BN (causal Toeplitz).
__global__ __launch_bounds__(256) void toep_gemm_fast(
    const ushort* __restrict__ Xc, const ushort* __restrict__ Wc,
    const float* __restrict__ bias, float* __restrict__ out)
{
    __shared__ __align__(16) ushort As[4 * BM * 8];   // [q][ml][8]
    __shared__ __align__(16) ushort Bs[4 * BN * 8];   // [q][nl][8]

    const int bx = blockIdx.x;
    const int jb = 7 - (bx >> 8);       // heavy column blocks dispatched first
    const int rb = bx & 255;
    const int m0 = rb * BM;
    const int j0 = jb * BN;
    const int n_iter = (j0 + BN) / BK;  // causal bound

    const int tid  = threadIdx.x;
    const int lane = tid & 63;
    const int wave = tid >> 6;
    const int wm   = (wave >> 1) * 64;
    const int wn   = (wave & 1) * 64;
    const int l15  = lane & 15;
    const int quad = lane >> 4;

    // staging geometry: thread t covers chunk q = t>>7 (and q+2), ml = t&127
    const int sq = tid >> 7;
    const int sl = tid & 127;
    const ushort* ga = Xc + ((size_t)sq * M_DIM + m0 + sl) * 8;
    const ushort* gb = Wc + ((size_t)sq * S_DIM + j0 + sl) * 8;
    ushort* la = As + wave * 512;       // wave-uniform LDS base (lane adds lane*16)
    ushort* lb = Bs + wave * 512;
    const size_t a_step = (size_t)4 * M_DIM * 8;   // ushorts per K-iter
    const size_t b_step = (size_t)4 * S_DIM * 8;
    const size_t a_q2   = (size_t)2 * M_DIM * 8;
    const size_t b_q2   = (size_t)2 * S_DIM * 8;

    f32x4 acc[4][4] = {};

    for (int it = 0; it < n_iter; ++it) {
        __builtin_amdgcn_global_load_lds((const AS1 void*)ga,          (AS3 void*)la,          16, 0, 0);
        __builtin_amdgcn_global_load_lds((const AS1 void*)(ga + a_q2), (AS3 void*)(la + 2048), 16, 0, 0);
        __builtin_amdgcn_global_load_lds((const AS1 void*)gb,          (AS3 void*)lb,          16, 0, 0);
        __builtin_amdgcn_global_load_lds((const AS1 void*)(gb + b_q2), (AS3 void*)(lb + 2048), 16, 0, 0);
        ga += a_step;
        gb += b_step;
        __syncthreads();

        bf16x8 af[4], bf[4];
#pragma unroll
        for (int im = 0; im < 4; ++im)
            af[im] = *reinterpret_cast<const bf16x8*>(&As[(size_t)(quad * BM + wm + im * 16 + l15) * 8]);
#pragma unroll
        for (int in = 0; in < 4; ++in)
            bf[in] = *reinterpret_cast<const bf16x8*>(&Bs[(size_t)(quad * BN + wn + in * 16 + l15) * 8]);
#pragma unroll
        for (int im = 0; im < 4; ++im)
#pragma unroll
            for (int in = 0; in < 4; ++in)
                acc[im][in] = __builtin_amdgcn_mfma_f32_16x16x32_bf16(af[im], bf[in], acc[im][in], 0, 0, 0);
        __syncthreads();
    }

    // epilogue: C/D mapping col = lane&15, row = quad*4 + r
#pragma unroll
    for (int in = 0; in < 4; ++in) {
        int col = j0 + wn + in * 16 + l15;
        float bv = bias[col];
#pragma unroll
        for (int im = 0; im < 4; ++im) {
            int mrow = m0 + wm + im * 16 + quad * 4;
            float* op = out + (size_t)mrow * S_DIM + col;
#pragma unroll
            for (int r = 0; r < 4; ++r)
                op[(size_t)r * S_DIM] = acc[im][in][r] + bv;
        }
    }
}

// ---------- fallback (round-1 kernel) for small ws_size ----------
__global__ __launch_bounds__(256) void toep_gemm_fb(
    const float* __restrict__ x, const ushort* __restrict__ Wc,
    const float* __restrict__ bias, float* __restrict__ out)
{
    __shared__ __align__(16) ushort As[4 * BM * 8];
    __shared__ __align__(16) ushort Bs[4 * BN * 8];

    const int bx = blockIdx.x;
    const int jb = 7 - (bx & 7);
    const int rb = bx >> 3;
    const int m0 = rb * BM;
    const int j0 = jb * BN;
    const int Kblk = j0 + BN;

    const int tid  = threadIdx.x;
    const int lane = tid & 63;
    const int wave = tid >> 6;
    const int wm   = (wave >> 1) * 64;
    const int wn   = (wave & 1) * 64;
    const int l15  = lane & 15;
    const int quad = lane >> 4;

    f32x4 acc[4][4] = {};

    const int a_sub_row = tid >> 3;
    const int a_kc      = tid & 7;
    const int a_q       = a_kc >> 1;
    const int a_sub     = a_kc & 1;
    const int b_n  = tid & 127;
    const int b_q  = tid >> 7;

    for (int k0 = 0; k0 < Kblk; k0 += BK) {
        f32x4 av[4];
#pragma unroll
        for (int i = 0; i < 4; ++i) {
            const float* gp = x + (size_t)(m0 + i * 32 + a_sub_row) * S_DIM + k0 + a_kc * 4;
            av[i] = *reinterpret_cast<const f32x4*>(gp);
        }
        {
            const int kq0 = k0 >> 3;
            const ushort* g0 = Wc + ((size_t)(kq0 + b_q)     * 1024 + j0 + b_n) * 8;
            const ushort* g1 = Wc + ((size_t)(kq0 + 2 + b_q) * 1024 + j0 + b_n) * 8;
            ushort* l0 = Bs + (size_t)(wave * 64) * 8;
            ushort* l1 = Bs + (size_t)(256 + wave * 64) * 8;
            __builtin_amdgcn_global_load_lds((const AS1 void*)g0, (AS3 void*)l0, 16, 0, 0);
            __builtin_amdgcn_global_load_lds((const AS1 void*)g1, (AS3 void*)l1, 16, 0, 0);
        }
#pragma unroll
        for (int i = 0; i < 4; ++i) {
            uint32_t p0 = pk_bf16(av[i][0], av[i][1]);
            uint32_t p1 = pk_bf16(av[i][2], av[i][3]);
            int row = i * 32 + a_sub_row;
            uint32_t* lp = reinterpret_cast<uint32_t*>(&As[(size_t)(a_q * BM + row) * 8 + a_sub * 4]);
            lp[0] = p0;
            lp[1] = p1;
        }
        __syncthreads();

        bf16x8 af[4], bf[4];
#pragma unroll
        for (int im = 0; im < 4; ++im)
            af[im] = *reinterpret_cast<const bf16x8*>(&As[(size_t)(quad * BM + wm + im * 16 + l15) * 8]);
#pragma unroll
        for (int in = 0; in < 4; ++in)
            bf[in] = *reinterpret_cast<const bf16x8*>(&Bs[(size_t)(quad * BN + wn + in * 16 + l15) * 8]);
#pragma unroll
        for (int im = 0; im < 4; ++im)
#pragma unroll
            for (int in = 0; in < 4; ++in)
                acc[im][in] = __builtin_amdgcn_mfma_f32_16x16x32_bf16(af[im], bf[in], acc[im][in], 0, 0, 0);
        __syncthreads();
    }

#pragma unroll
    for (int in = 0; in < 4; ++in) {
        int col = j0 + wn + in * 16 + l15;
        float bv = bias[col];
#pragma unroll
        for (int im = 0; im < 4; ++im) {
            int mrow = m0 + wm + im * 16 + quad * 4;
            float* op = out + (size_t)mrow * S_DIM + col;
#pragma unroll
            for (int r = 0; r < 4; ++r)
                op[(size_t)r * S_DIM] = acc[im][in][r] + bv;
        }
    }
}

extern "C" void kernel_launch(void* const* d_in, const int* in_sizes, int n_in,
                              void* d_out, int out_size, void* d_ws, size_t ws_size,
                              hipStream_t stream) {
    const float* x      = (const float*)d_in[0];   // (32, 1024, 1024) fp32
    const float* weight = (const float*)d_in[1];   // (1, 1024) fp32
    const float* bias   = (const float*)d_in[2];   // (1024,) fp32
    float* out          = (float*)d_out;           // (32, 1024, 1024) fp32

    ushort* Wc = (ushort*)d_ws;                                   // 2 MB
    const size_t WC_BYTES = (size_t)128 * 1024 * 16;              // 2,097,152
    const size_t XC_BYTES = (size_t)128 * M_DIM * 16;             // 67,108,864

    build_wc<<<512, 256, 0, stream>>>(weight, Wc);

    if (ws_size >= WC_BYTES + XC_BYTES) {
        ushort* Xc = (ushort*)((char*)d_ws + WC_BYTES);
        convert_x<<<8192, 256, 0, stream>>>(x, Xc);
        toep_gemm_fast<<<2048, 256, 0, stream>>>(Xc, Wc, bias, out);
    } else {
        toep_gemm_fb<<<2048, 256, 0, stream>>>(x, Wc, bias, out);
    }
}

// Round 3
// 300.094 us; speedup vs baseline: 1.1837x; 1.0957x over previous
//
#include <hip/hip_runtime.h>
#include <stdint.h>

typedef __bf16 bf16x8 __attribute__((ext_vector_type(8)));
typedef float  f32x4  __attribute__((ext_vector_type(4)));

static constexpr int S_DIM = 1024;   // sequence length (= N = K)

// RNE fp32 -> bf16
__device__ __forceinline__ ushort f32_to_bf16_rne(float f) {
    uint32_t u = __builtin_bit_cast(uint32_t, f);
    u += 0x7fffu + ((u >> 16) & 1u);
    return (ushort)(u >> 16);
}
__device__ __forceinline__ uint32_t pk_bf16(float a, float b) {
    return (uint32_t)f32_to_bf16_rne(a) | ((uint32_t)f32_to_bf16_rne(b) << 16);
}

// Wc[kq][j][8] bf16 chunks: chunk (kq, j)[e] = W[kq*8+e][j],
// W[k][j] = (j >= k) ? w[j-k] : 0.  (2 MB, stays L2-resident.)
__global__ void build_wc(const float* __restrict__ w, ushort* __restrict__ Wc) {
    int c  = blockIdx.x * 256 + threadIdx.x;   // kq*1024 + j
    int kq = c >> 10;
    int j  = c & 1023;
    uint32_t p[4];
#pragma unroll
    for (int h = 0; h < 4; ++h) {
        int d0 = j - (kq * 8 + h * 2);
        int d1 = d0 - 1;
        float v0 = (d0 >= 0) ? w[d0] : 0.0f;
        float v1 = (d1 >= 0) ? w[d1] : 0.0f;
        p[h] = (uint32_t)f32_to_bf16_rne(v0) | ((uint32_t)f32_to_bf16_rne(v1) << 16);
    }
    reinterpret_cast<uint4*>(Wc)[c] = make_uint4(p[0], p[1], p[2], p[3]);
}

// Row-panel kernel: each block owns 32 rows x ALL 1024 cols.
// x read ONCE (fp32 -> bf16 in-reg -> 2KB LDS dbuf, 1 barrier/iter).
// B frags loaded straight from L2-hot Wc into registers (no LDS).
// Causal skip per 16-col fragment; cols interleaved across waves (jc = f*4+w)
// so all 4 waves stay balanced at every K-step.
__global__ __launch_bounds__(256, 2) void toep_rowpanel(
    const float* __restrict__ x, const ushort* __restrict__ Wc,
    const float* __restrict__ bias, float* __restrict__ out)
{
    __shared__ __align__(16) ushort As[2][1024];   // [buf][q*256 + m*8 + e], 2 KB each

    const int tid  = threadIdx.x;
    const int lane = tid & 63;
    const int w    = tid >> 6;        // wave 0..3
    const int l15  = lane & 15;
    const int quad = lane >> 4;
    const int m0   = blockIdx.x * 32;

    // A staging: thread covers row sm = tid>>3, k-chunk kc = tid&7 (4 fp32, 16B)
    const int sm = tid >> 3;
    const int kc = tid & 7;
    const float* gx = x + (size_t)(m0 + sm) * S_DIM + kc * 4;
    // LDS write slot (ushort index): q = kc>>1, element base (kc&1)*4
    const int aw = (kc >> 1) * 256 + sm * 8 + (kc & 1) * 4;

    // B per-lane base (ushort index): kq = quad, col = w*16 + l15 part
    const ushort* gb = Wc + (size_t)quad * 8192 + w * 128 + l15 * 8;

    // A-frag read slots (ushort index): chunk (quad, im*16 + l15)
    const int ar0 = quad * 256 + l15 * 8;
    const int ar1 = ar0 + 128;

    f32x4 acc[16][2] = {};   // [frag f][row-frag im], 128 VGPR

    f32x4 av0 = __builtin_nontemporal_load(reinterpret_cast<const f32x4*>(gx));
    f32x4 av1 = __builtin_nontemporal_load(reinterpret_cast<const f32x4*>(gx + 32));

    for (int it = 0; it < 32; ++it) {
        const int p = it & 1;
        // prefetch A two iterations ahead (clamped; redundant at the tail)
        int itn = it + 2; if (itn > 31) itn = 31;
        f32x4 avn = __builtin_nontemporal_load(reinterpret_cast<const f32x4*>(gx + itn * 32));

        // convert current A 16B -> 8B bf16, write LDS
        uint32_t c0 = pk_bf16(av0[0], av0[1]);
        uint32_t c1 = pk_bf16(av0[2], av0[3]);
        *reinterpret_cast<uint2*>(&As[p][aw]) = make_uint2(c0, c1);

        // causal fragment cutoff for this wave (wave-uniform)
        const int t2   = it * 2;                               // k0 / 16
        const int f_lo = (t2 > w) ? ((t2 - w + 3) >> 2) : 0;   // first live frag
        const bool g0 = f_lo < 4, g1 = f_lo < 8, g2 = f_lo < 12, g3 = f_lo < 16;

        // issue ALL live B chunk loads up front (<=16 outstanding b128 from L2)
        const ushort* gbit = gb + (size_t)it * 32768;
        bf16x8 bf[4][4];
        if (g0) {
#pragma unroll
            for (int i = 0; i < 4; ++i)
                bf[0][i] = *reinterpret_cast<const bf16x8*>(gbit + 0 * 2048 + i * 512);
        }
        if (g1) {
#pragma unroll
            for (int i = 0; i < 4; ++i)
                bf[1][i] = *reinterpret_cast<const bf16x8*>(gbit + 1 * 2048 + i * 512);
        }
        if (g2) {
#pragma unroll
            for (int i = 0; i < 4; ++i)
                bf[2][i] = *reinterpret_cast<const bf16x8*>(gbit + 2 * 2048 + i * 512);
        }
        if (g3) {
#pragma unroll
            for (int i = 0; i < 4; ++i)
                bf[3][i] = *reinterpret_cast<const bf16x8*>(gbit + 3 * 2048 + i * 512);
        }

        __syncthreads();   // A tile (buf p) visible; single barrier per iter (dbuf-safe)

        bf16x8 af0 = *reinterpret_cast<const bf16x8*>(&As[p][ar0]);
        bf16x8 af1 = *reinterpret_cast<const bf16x8*>(&As[p][ar1]);

        if (g0) {
#pragma unroll
            for (int i = 0; i < 4; ++i) {
                acc[0 + i][0] = __builtin_amdgcn_mfma_f32_16x16x32_bf16(af0, bf[0][i], acc[0 + i][0], 0, 0, 0);
                acc[0 + i][1] = __builtin_amdgcn_mfma_f32_16x16x32_bf16(af1, bf[0][i], acc[0 + i][1], 0, 0, 0);
            }
        }
        if (g1) {
#pragma unroll
            for (int i = 0; i < 4; ++i) {
                acc[4 + i][0] = __builtin_amdgcn_mfma_f32_16x16x32_bf16(af0, bf[1][i], acc[4 + i][0], 0, 0, 0);
                acc[4 + i][1] = __builtin_amdgcn_mfma_f32_16x16x32_bf16(af1, bf[1][i], acc[4 + i][1], 0, 0, 0);
            }
        }
        if (g2) {
#pragma unroll
            for (int i = 0; i < 4; ++i) {
                acc[8 + i][0] = __builtin_amdgcn_mfma_f32_16x16x32_bf16(af0, bf[2][i], acc[8 + i][0], 0, 0, 0);
                acc[8 + i][1] = __builtin_amdgcn_mfma_f32_16x16x32_bf16(af1, bf[2][i], acc[8 + i][1], 0, 0, 0);
            }
        }
        if (g3) {
#pragma unroll
            for (int i = 0; i < 4; ++i) {
                acc[12 + i][0] = __builtin_amdgcn_mfma_f32_16x16x32_bf16(af0, bf[3][i], acc[12 + i][0], 0, 0, 0);
                acc[12 + i][1] = __builtin_amdgcn_mfma_f32_16x16x32_bf16(af1, bf[3][i], acc[12 + i][1], 0, 0, 0);
            }
        }

        av0 = av1; av1 = avn;
    }

    // epilogue: C/D mapping col = lane&15, row = quad*4 + r (verified m89/m91)
#pragma unroll
    for (int f = 0; f < 16; ++f) {
        const int col = (f * 4 + w) * 16 + l15;
        const float bv = bias[col];
#pragma unroll
        for (int im = 0; im < 2; ++im) {
            const int row0 = m0 + im * 16 + quad * 4;
            float* op = out + (size_t)row0 * S_DIM + col;
#pragma unroll
            for (int r = 0; r < 4; ++r)
                __builtin_nontemporal_store(acc[f][im][r] + bv, op + (size_t)r * S_DIM);
        }
    }
}

extern "C" void kernel_launch(void* const* d_in, const int* in_sizes, int n_in,
                              void* d_out, int out_size, void* d_ws, size_t ws_size,
                              hipStream_t stream) {
    const float* x      = (const float*)d_in[0];   // (32, 1024, 1024) fp32
    const float* weight = (const float*)d_in[1];   // (1, 1024) fp32
    const float* bias   = (const float*)d_in[2];   // (1024,) fp32
    float* out          = (float*)d_out;           // (32, 1024, 1024) fp32

    ushort* Wc = (ushort*)d_ws;                    // 2 MB bf16 Toeplitz, chunked

    build_wc<<<512, 256, 0, stream>>>(weight, Wc);
    toep_rowpanel<<<1024, 256, 0, stream>>>(x, Wc, bias, out);
}